// Round 7
// baseline (5699.831 us; speedup 1.0000x reference)
//
#include <hip/hip_runtime.h>
#include <stdint.h>

// EISepLSTM: x(T,B,I) -> ig GEMM -> 512-step EI recurrence -> out GEMM.
// T=512, B=128, I=H=O=512.
// Round 7: recurrence fully intra-CU (8 blocks, one per 16-batch group).
// Wrec row-quantized to int8 (per-output-row scale = rowmax/127): 256 KB =
// 128 reg-equivs (bregs[4][8] -> unified AGPR file) + 128 KB LDS. a_t = h*ei
// quantized to i8 at fixed scale 1/16. MFMA i32_16x16x64_i8 (K=64, 64/step).
// One __syncthreads per step. No cross-block traffic at all.

typedef __attribute__((ext_vector_type(8))) short short8;
typedef __attribute__((ext_vector_type(4))) float f32x4;
typedef __attribute__((ext_vector_type(4))) int int4x;

__device__ __forceinline__ unsigned short f2b(float f) {
  unsigned int u = __float_as_uint(f);
  u = (u + 0x7fffu + ((u >> 16) & 1u)) >> 16;   // RNE
  return (unsigned short)u;
}
__device__ __forceinline__ float b2f(unsigned short s) {
  return __uint_as_float(((unsigned int)s) << 16);
}

// ---------------- prep: ei2 (permuted), bf16 weight casts, c_last ----------
__global__ void prep_kernel(const float* __restrict__ gu,      // (T,H,2)
                            const float* __restrict__ logit,   // (H,2)
                            const float* __restrict__ win,     // (H,I)
                            const float* __restrict__ wout,    // (O,H)
                            float* __restrict__ ei2,           // permuted
                            unsigned short* __restrict__ winb,
                            unsigned short* __restrict__ woutb,
                            float* __restrict__ c_last) {
  int i = blockIdx.x * 256 + threadIdx.x;          // 0 .. 262143
  int t = i >> 9, h = i & 511;
  float u0 = gu[2 * i], u1 = gu[2 * i + 1];
  float l0 = logit[2 * h], l1 = logit[2 * h + 1];
  float g0 = -logf(-logf(u0 + 1e-10f) + 1e-10f);
  float g1 = -logf(-logf(u1 + 1e-10f) + 1e-10f);
  // softmax2 diff == tanh(dz/2), dz = ((l0+g0)-(l1+g1))/tau
  float dz = ((l0 + g0) - (l1 + g1)) * 10.0f;
  float v = tanhf(0.5f * dz);
  // ei2[(t,w,l=lq*16+lm)][j] = ei[t][w*128+j*16+lm], replicated over lq
  int w = h >> 7, j = (h >> 4) & 7, lm = h & 15;
  size_t base = ((size_t)t * 4 + w) * 64;
#pragma unroll
  for (int lq = 0; lq < 4; ++lq)
    ei2[(base + lq * 16 + lm) * 8 + j] = v;
  winb[i]  = f2b(win[i]);
  woutb[i] = f2b(wout[i]);
  if (i < 65536) c_last[i] = 0.0f;
}

// ---------------- Wrec row quantization: i8 with per-row scale -------------
__global__ void wquant_kernel(const float* __restrict__ wrec,  // (H,H)
                              char* __restrict__ wrec8,        // (H,H) i8
                              float* __restrict__ wscale) {    // (H)
  const int n = blockIdx.x;          // output row 0..511
  const int l = threadIdx.x;         // 0..63
  const float* row = wrec + (size_t)n * 512 + l * 8;
  float v[8];
  float m = 0.f;
#pragma unroll
  for (int e = 0; e < 8; ++e) {
    v[e] = fmaxf(row[e], 0.f);
    m = fmaxf(m, v[e]);
  }
#pragma unroll
  for (int off = 32; off >= 1; off >>= 1) m = fmaxf(m, __shfl_down(m, off));
  m = __shfl(m, 0);
  const float s = (m > 0.f) ? (m / 127.f) : 1.f;
  const float inv = 1.f / s;
  unsigned long long pk = 0;
#pragma unroll
  for (int e = 0; e < 8; ++e) {
    int q = (int)rintf(v[e] * inv);
    pk |= ((unsigned long long)(unsigned char)(char)q) << (8 * e);
  }
  *(unsigned long long*)(wrec8 + (size_t)n * 512 + l * 8) = pk;
  if (l == 0) wscale[n] = s;
}

// ---------------- GEMM: C[m,n] = sum_k A[m,k]*W[n,k] + bias[n] -------------
// A: M x 512 (f32 or bf16), W: 512 x 512 bf16 row-major, out f32 or bf16.
// PERM: write bf16 out in the recurrence's lane-permuted ig layout.
template <int A_F32, int OUT_BF16, int PERM>
__global__ __launch_bounds__(256, 2) void gemm512(
    const void* __restrict__ Ap, const unsigned short* __restrict__ W,
    const float* __restrict__ bias, void* __restrict__ Cp) {
  __shared__ __align__(16) unsigned short Al[128][32];
  __shared__ __align__(16) unsigned short Bl[128][32];
  const int tid = threadIdx.x;
  const int w = tid >> 6, l = tid & 63;
  const int wr = w >> 1, wc = w & 1;
  const int lm = l & 15, lq = l >> 4;
  const size_t m0 = (size_t)blockIdx.x * 128;
  const int n0 = blockIdx.y * 128;
  const int r = tid >> 1;             // staging row 0..127
  const int sb = (tid & 1) << 1;      // staging slot base (16B slots): 0 or 2
  f32x4 acc[4][4] = {};

  for (int kt = 0; kt < 16; ++kt) {
    const int k0 = kt << 5;
    // stage A tile
    {
      char* dst = (char*)Al + r * 64;
      if (A_F32) {
        const float* A = (const float*)Ap + (m0 + r) * 512 + k0 + (sb << 3);
#pragma unroll
        for (int j = 0; j < 2; ++j) {
          float4 v0 = ((const float4*)A)[2 * j + 0];
          float4 v1 = ((const float4*)A)[2 * j + 1];
          short8 o;
          o[0] = (short)f2b(v0.x); o[1] = (short)f2b(v0.y);
          o[2] = (short)f2b(v0.z); o[3] = (short)f2b(v0.w);
          o[4] = (short)f2b(v1.x); o[5] = (short)f2b(v1.y);
          o[6] = (short)f2b(v1.z); o[7] = (short)f2b(v1.w);
          *(short8*)(dst + (((sb + j + (r >> 1)) & 3) << 4)) = o;
        }
      } else {
        const unsigned short* A =
            (const unsigned short*)Ap + (m0 + r) * 512 + k0 + (sb << 3);
#pragma unroll
        for (int j = 0; j < 2; ++j)
          *(short8*)(dst + (((sb + j + (r >> 1)) & 3) << 4)) =
              *(const short8*)(A + 8 * j);
      }
      // stage W tile
      const unsigned short* Wp = W + ((size_t)(n0 + r) << 9) + k0 + (sb << 3);
      char* dstB = (char*)Bl + r * 64;
#pragma unroll
      for (int j = 0; j < 2; ++j)
        *(short8*)(dstB + (((sb + j + (r >> 1)) & 3) << 4)) =
            *(const short8*)(Wp + 8 * j);
    }
    __syncthreads();
    short8 af[4], bf[4];
#pragma unroll
    for (int i = 0; i < 4; ++i) {
      int row = wr * 64 + i * 16 + lm;
      af[i] = *(const short8*)((char*)Al + row * 64 +
                               (((lq + (row >> 1)) & 3) << 4));
    }
#pragma unroll
    for (int j = 0; j < 4; ++j) {
      int row = wc * 64 + j * 16 + lm;
      bf[j] = *(const short8*)((char*)Bl + row * 64 +
                               (((lq + (row >> 1)) & 3) << 4));
    }
#pragma unroll
    for (int i = 0; i < 4; ++i)
#pragma unroll
      for (int j = 0; j < 4; ++j)
        acc[i][j] =
            __builtin_amdgcn_mfma_f32_16x16x32_bf16(af[i], bf[j], acc[i][j], 0, 0, 0);
    __syncthreads();
  }
  float bv[4];
#pragma unroll
  for (int j = 0; j < 4; ++j) bv[j] = bias[n0 + wc * 64 + j * 16 + lm];
#pragma unroll
  for (int i = 0; i < 4; ++i) {
#pragma unroll
    for (int r4 = 0; r4 < 4; ++r4) {
      size_t gm = m0 + wr * 64 + i * 16 + lq * 4 + r4;
#pragma unroll
      for (int j = 0; j < 4; ++j) {
        int gn = n0 + wc * 64 + j * 16 + lm;
        float v = acc[i][j][r4] + bv[j];
        if (OUT_BF16) {
          if (PERM) {
            // ig layout: [t][g][w][lane][j*4+r4]
            int b2 = (int)gm & 127;
            int g2 = b2 >> 4, mm = b2 & 15;
            int l2 = ((mm >> 2) << 4) | (gn & 15);
            size_t idx =
                ((((size_t)(gm >> 7) * 8 + g2) * 4 + (size_t)(gn >> 7)) * 64 +
                 l2) * 32 + (((gn >> 4) & 7) << 2) + (mm & 3);
            ((unsigned short*)Cp)[idx] = f2b(v);
          } else {
            ((unsigned short*)Cp)[(gm << 9) + gn] = f2b(v);
          }
        } else {
          ((float*)Cp)[(gm << 9) + gn] = v;
        }
      }
    }
  }
}

// ---------------- recurrence (intra-CU, i8) --------------------------------
// grid = 8; block g handles batches [16g,16g+16), full H=512.
// wave w owns cols [128w,128w+128) = 8 n-tiles. K=64 MFMA chunks: kk 0..3 in
// registers (bregs[4][8], 128 reg-equivs), kk 4..7 in LDS (128 KB).
// a_t i8 tile As[2][16][512] (16 KB), slot-swizzled; 1 barrier/step.
__global__ __launch_bounds__(256, 1) void recur7_kernel(
    const unsigned short* __restrict__ igh,  // permuted ig bf16
    const float* __restrict__ ei2,           // permuted ei f32
    const char* __restrict__ wrec8,          // (H,H) i8
    const float* __restrict__ wscale,        // (H) f32
    const float* __restrict__ rbias,         // (H)
    unsigned short* __restrict__ hs,         // (T*B,512) bf16 plain
    float* __restrict__ h_last) {            // (B,H) f32
  __shared__ __align__(16) int4x Bls[4][4][8][64];   // 128 KB
  __shared__ __align__(16) char As[2][16][512];      // 16 KB
  const int tid = threadIdx.x;
  const int g = blockIdx.x;
  const int bb = g << 4;
  const int w = tid >> 6, l = tid & 63;
  const int lm = l & 15, lq = l >> 4;
  const int nbase = w << 7;
  const int lswz = lm & 7;

  // weights: kk 0..3 -> registers, kk 4..7 -> LDS
  int4x bregs[4][8];
#pragma unroll
  for (int kk = 0; kk < 4; ++kk)
#pragma unroll
    for (int j = 0; j < 8; ++j)
      bregs[kk][j] = *(const int4x*)(
          wrec8 + ((size_t)(nbase + j * 16 + lm) << 9) + (kk << 6) + (lq << 4));
#pragma unroll
  for (int kk = 4; kk < 8; ++kk)
#pragma unroll
    for (int j = 0; j < 8; ++j)
      Bls[w][kk - 4][j][l] = *(const int4x*)(
          wrec8 + ((size_t)(nbase + j * 16 + lm) << 9) + (kk << 6) + (lq << 4));
  float wsc[8], rb[8];
#pragma unroll
  for (int j = 0; j < 8; ++j) {
    wsc[j] = wscale[nbase + j * 16 + lm] * 0.0625f;   // * (1/16) a-scale
    rb[j]  = rbias[nbase + j * 16 + lm];
  }
  // zero both As parities (h0 = 0): 16384 B / 256 threads = 64 B each
  {
    int4x z = {0, 0, 0, 0};
#pragma unroll
    for (int q = 0; q < 4; ++q)
      *(int4x*)((char*)As + tid * 64 + q * 16) = z;
  }
  __syncthreads();

#pragma unroll 1
  for (int t = 0; t < 512; ++t) {
    const int par = t & 1, par2 = par ^ 1;
    // ig[t]: one contiguous 64B load per lane (permuted layout)
    const unsigned short* igp =
        igh + ((((size_t)t * 8 + g) * 4 + w) * 64 + l) * 32;
    short8 igv[4];
    igv[0] = *(const short8*)(igp);
    igv[1] = *(const short8*)(igp + 8);
    igv[2] = *(const short8*)(igp + 16);
    igv[3] = *(const short8*)(igp + 24);
    f32x4 eif0 = {0.f, 0.f, 0.f, 0.f}, eif1 = {0.f, 0.f, 0.f, 0.f};
    if (t < 511) {
      const float* eip = ei2 + ((((size_t)(t + 1) * 4 + w) * 64 + l) << 3);
      eif0 = *(const f32x4*)(eip);
      eif1 = *(const f32x4*)(eip + 4);
    }

    int4x acc[8] = {};
    const char* aRow = (const char*)As + par * 8192 + lm * 512;
#pragma unroll
    for (int kk = 0; kk < 4; ++kk) {
      int4x av = *(const int4x*)(aRow + ((((kk << 2) | lq) ^ lswz) << 4));
#pragma unroll
      for (int j = 0; j < 8; ++j)
        acc[j] = __builtin_amdgcn_mfma_i32_16x16x64_i8(av, bregs[kk][j],
                                                       acc[j], 0, 0, 0);
    }
#pragma unroll
    for (int kk = 4; kk < 8; ++kk) {
      int4x av = *(const int4x*)(aRow + ((((kk << 2) | lq) ^ lswz) << 4));
#pragma unroll
      for (int j = 0; j < 8; ++j)
        acc[j] = __builtin_amdgcn_mfma_i32_16x16x64_i8(av, Bls[w][kk - 4][j][l],
                                                       acc[j], 0, 0, 0);
    }

    // epilogue: h = softplus(acc*scale + ig + rb); emit hs/h_last; a_{t+1}
#pragma unroll
    for (int j = 0; j < 8; ++j) {
      const int n = nbase + (j << 4) + lm;
      const float eiv = (j < 4) ? eif0[j] : eif1[j - 4];
#pragma unroll
      for (int r4 = 0; r4 < 4; ++r4) {
        const int mm = (lq << 2) + r4;
        float z = (float)acc[j][r4] * wsc[j] +
                  b2f((unsigned short)igv[j >> 1][((j & 1) << 2) + r4]) + rb[j];
        float h = (z > 20.f) ? z : log1pf(__expf(z));
        __builtin_nontemporal_store(
            f2b(h), hs + (((size_t)(t << 7) + bb + mm) << 9) + n);
        if (t == 511) {
          h_last[((bb + mm) << 9) + n] = h;
        } else {
          float a = h * eiv * 16.f;
          int ai = (int)rintf(fminf(fmaxf(a, -127.f), 127.f));
          ((char*)As)[par2 * 8192 + mm * 512 +
                      ((((n >> 4) ^ (mm & 7)) << 4) | (n & 15))] = (char)ai;
        }
      }
    }
    __syncthreads();   // a_{t+1} writes visible before next step's K-loop
  }
}

// ---------------- launch ---------------------------------------------------
extern "C" void kernel_launch(void* const* d_in, const int* in_sizes, int n_in,
                              void* d_out, int out_size, void* d_ws,
                              size_t ws_size, hipStream_t stream) {
  const float* x     = (const float*)d_in[0];
  const float* gu    = (const float*)d_in[1];
  const float* Win   = (const float*)d_in[2];
  const float* bin   = (const float*)d_in[3];
  const float* Wrec  = (const float*)d_in[4];
  const float* rbias = (const float*)d_in[5];
  const float* elog  = (const float*)d_in[6];
  const float* Wout  = (const float*)d_in[7];
  const float* bout  = (const float*)d_in[8];

  char* ws = (char*)d_ws;
  float* ei2            = (float*)ws;                        // 4 MB
  unsigned short* winb  = (unsigned short*)(ws + 4194304);   // 512 KB
  unsigned short* woutb = (unsigned short*)(ws + 4718592);   // 512 KB
  char* wrec8           = (char*)(ws + 5242880);             // 256 KB
  float* wscale         = (float*)(ws + 5505024);            // 2 KB
  unsigned short* igh   = (unsigned short*)(ws + 6291456);   // 64 MB
  unsigned short* hs    = (unsigned short*)(ws + 73400320);  // 64 MB

  float* outp  = (float*)d_out;            // (T,B,O) f32
  float* hlast = outp + 33554432;          // (B,H)
  float* clast = outp + 33554432 + 65536;  // (B,H) zeros

  prep_kernel<<<1024, 256, 0, stream>>>(gu, elog, Win, Wout, ei2, winb, woutb,
                                        clast);
  wquant_kernel<<<512, 64, 0, stream>>>(Wrec, wrec8, wscale);
  gemm512<1, 1, 1><<<dim3(512, 4), 256, 0, stream>>>(x, winb, bin, igh);
  recur7_kernel<<<8, 256, 0, stream>>>(igh, ei2, wrec8, wscale, rbias, hs,
                                       hlast);
  gemm512<0, 0, 0><<<dim3(512, 4), 256, 0, stream>>>(hs, woutb, bout, outp);
}

// Round 8
// 785.091 us; speedup vs baseline: 7.2601x; 7.2601x over previous
//
#include <hip/hip_runtime.h>
#include <stdint.h>

// EISepLSTM: x(T,B,I) -> ig GEMM -> 512-step EI recurrence -> out GEMM.
// T=512, B=128, I=H=O=512.
// Round 8: intra-CU recurrence spread over 32 CUs. Block = 4 batch rows x
// full H=512, 512 threads (8 waves, 2/SIMD). Wave owns 64 cols; its i8
// weights (64x512 = 32 KB = 128 VGPR) are FULLY register-resident -> no
// weight LDS traffic. a_t i8 tile in LDS (16 KB) + per-wave redistribute
// buffer (8.5 KB). Fast native softplus. One barrier/step. No cross-block
// communication.

typedef __attribute__((ext_vector_type(8))) short short8;
typedef __attribute__((ext_vector_type(4))) float f32x4;
typedef __attribute__((ext_vector_type(4))) int int4x;

__device__ __forceinline__ unsigned short f2b(float f) {
  unsigned int u = __float_as_uint(f);
  u = (u + 0x7fffu + ((u >> 16) & 1u)) >> 16;   // RNE
  return (unsigned short)u;
}
__device__ __forceinline__ float b2f(unsigned short s) {
  return __uint_as_float(((unsigned int)s) << 16);
}

// ---------------- prep: ei2 (permuted), bf16 weight casts, c_last ----------
// ei2 layout (T,8,64): ei2[(t*8+w)*64 + (jl*16+lm)] = ei[t][w*64+jl*16+lm]
__global__ void prep_kernel(const float* __restrict__ gu,      // (T,H,2)
                            const float* __restrict__ logit,   // (H,2)
                            const float* __restrict__ win,     // (H,I)
                            const float* __restrict__ wout,    // (O,H)
                            float* __restrict__ ei2,           // permuted
                            unsigned short* __restrict__ winb,
                            unsigned short* __restrict__ woutb,
                            float* __restrict__ c_last) {
  int i = blockIdx.x * 256 + threadIdx.x;          // 0 .. 262143
  int t = i >> 9, h = i & 511;
  float u0 = gu[2 * i], u1 = gu[2 * i + 1];
  float l0 = logit[2 * h], l1 = logit[2 * h + 1];
  float g0 = -logf(-logf(u0 + 1e-10f) + 1e-10f);
  float g1 = -logf(-logf(u1 + 1e-10f) + 1e-10f);
  // softmax2 diff == tanh(dz/2), dz = ((l0+g0)-(l1+g1))/tau
  float dz = ((l0 + g0) - (l1 + g1)) * 10.0f;
  float v = tanhf(0.5f * dz);
  int w = h >> 6, jl = (h >> 4) & 3, lm = h & 15;
  ei2[((size_t)(t * 8 + w) << 6) + jl * 16 + lm] = v;
  winb[i]  = f2b(win[i]);
  woutb[i] = f2b(wout[i]);
  if (i < 65536) c_last[i] = 0.0f;
}

// ---------------- Wrec row quantization: i8 with per-row scale -------------
__global__ void wquant_kernel(const float* __restrict__ wrec,  // (H,H)
                              char* __restrict__ wrec8,        // (H,H) i8
                              float* __restrict__ wscale) {    // (H)
  const int n = blockIdx.x;          // output row 0..511
  const int l = threadIdx.x;         // 0..63
  const float* row = wrec + (size_t)n * 512 + l * 8;
  float v[8];
  float m = 0.f;
#pragma unroll
  for (int e = 0; e < 8; ++e) {
    v[e] = fmaxf(row[e], 0.f);
    m = fmaxf(m, v[e]);
  }
#pragma unroll
  for (int off = 32; off >= 1; off >>= 1) m = fmaxf(m, __shfl_down(m, off));
  m = __shfl(m, 0);
  const float s = (m > 0.f) ? (m / 127.f) : 1.f;
  const float inv = 1.f / s;
  unsigned long long pk = 0;
#pragma unroll
  for (int e = 0; e < 8; ++e) {
    int q = (int)rintf(v[e] * inv);
    pk |= ((unsigned long long)(unsigned char)(char)q) << (8 * e);
  }
  *(unsigned long long*)(wrec8 + (size_t)n * 512 + l * 8) = pk;
  if (l == 0) wscale[n] = s;
}

// ---------------- GEMM: C[m,n] = sum_k A[m,k]*W[n,k] + bias[n] -------------
// PERM: write bf16 out in recurrence ig layout (T,32,8,64,4):
//   idx = (((t*32+g)*8+w)*64 + (jl*16+lm))*4 + r,  g=b>>2, r=b&3,
//   w=gn>>6, jl=(gn>>4)&3, lm=gn&15.
template <int A_F32, int OUT_BF16, int PERM>
__global__ __launch_bounds__(256, 2) void gemm512(
    const void* __restrict__ Ap, const unsigned short* __restrict__ W,
    const float* __restrict__ bias, void* __restrict__ Cp) {
  __shared__ __align__(16) unsigned short Al[128][32];
  __shared__ __align__(16) unsigned short Bl[128][32];
  const int tid = threadIdx.x;
  const int w = tid >> 6, l = tid & 63;
  const int wr = w >> 1, wc = w & 1;
  const int lm = l & 15, lq = l >> 4;
  const size_t m0 = (size_t)blockIdx.x * 128;
  const int n0 = blockIdx.y * 128;
  const int r = tid >> 1;             // staging row 0..127
  const int sb = (tid & 1) << 1;      // staging slot base (16B slots): 0 or 2
  f32x4 acc[4][4] = {};

  for (int kt = 0; kt < 16; ++kt) {
    const int k0 = kt << 5;
    // stage A tile
    {
      char* dst = (char*)Al + r * 64;
      if (A_F32) {
        const float* A = (const float*)Ap + (m0 + r) * 512 + k0 + (sb << 3);
#pragma unroll
        for (int j = 0; j < 2; ++j) {
          float4 v0 = ((const float4*)A)[2 * j + 0];
          float4 v1 = ((const float4*)A)[2 * j + 1];
          short8 o;
          o[0] = (short)f2b(v0.x); o[1] = (short)f2b(v0.y);
          o[2] = (short)f2b(v0.z); o[3] = (short)f2b(v0.w);
          o[4] = (short)f2b(v1.x); o[5] = (short)f2b(v1.y);
          o[6] = (short)f2b(v1.z); o[7] = (short)f2b(v1.w);
          *(short8*)(dst + (((sb + j + (r >> 1)) & 3) << 4)) = o;
        }
      } else {
        const unsigned short* A =
            (const unsigned short*)Ap + (m0 + r) * 512 + k0 + (sb << 3);
#pragma unroll
        for (int j = 0; j < 2; ++j)
          *(short8*)(dst + (((sb + j + (r >> 1)) & 3) << 4)) =
              *(const short8*)(A + 8 * j);
      }
      // stage W tile
      const unsigned short* Wp = W + ((size_t)(n0 + r) << 9) + k0 + (sb << 3);
      char* dstB = (char*)Bl + r * 64;
#pragma unroll
      for (int j = 0; j < 2; ++j)
        *(short8*)(dstB + (((sb + j + (r >> 1)) & 3) << 4)) =
            *(const short8*)(Wp + 8 * j);
    }
    __syncthreads();
    short8 af[4], bf[4];
#pragma unroll
    for (int i = 0; i < 4; ++i) {
      int row = wr * 64 + i * 16 + lm;
      af[i] = *(const short8*)((char*)Al + row * 64 +
                               (((lq + (row >> 1)) & 3) << 4));
    }
#pragma unroll
    for (int j = 0; j < 4; ++j) {
      int row = wc * 64 + j * 16 + lm;
      bf[j] = *(const short8*)((char*)Bl + row * 64 +
                               (((lq + (row >> 1)) & 3) << 4));
    }
#pragma unroll
    for (int i = 0; i < 4; ++i)
#pragma unroll
      for (int j = 0; j < 4; ++j)
        acc[i][j] =
            __builtin_amdgcn_mfma_f32_16x16x32_bf16(af[i], bf[j], acc[i][j], 0, 0, 0);
    __syncthreads();
  }
  float bv[4];
#pragma unroll
  for (int j = 0; j < 4; ++j) bv[j] = bias[n0 + wc * 64 + j * 16 + lm];
#pragma unroll
  for (int i = 0; i < 4; ++i) {
#pragma unroll
    for (int r4 = 0; r4 < 4; ++r4) {
      size_t gm = m0 + wr * 64 + i * 16 + lq * 4 + r4;
#pragma unroll
      for (int j = 0; j < 4; ++j) {
        int gn = n0 + wc * 64 + j * 16 + lm;
        float v = acc[i][j][r4] + bv[j];
        if (OUT_BF16) {
          if (PERM) {
            int t2 = (int)(gm >> 7);
            int b2 = (int)gm & 127;
            int g2 = b2 >> 2, rr = b2 & 3;
            int w2 = gn >> 6, jl = (gn >> 4) & 3, lm2 = gn & 15;
            size_t idx =
                ((((size_t)t2 * 32 + g2) * 8 + w2) * 64 + jl * 16 + lm2) * 4 +
                rr;
            ((unsigned short*)Cp)[idx] = f2b(v);
          } else {
            ((unsigned short*)Cp)[(gm << 9) + gn] = f2b(v);
          }
        } else {
          ((float*)Cp)[(gm << 9) + gn] = v;
        }
      }
    }
  }
}

// ---------------- recurrence (intra-CU, i8, 32 blocks x 8 waves) -----------
// block g: batch rows [4g,4g+4), full H. wave w: cols [64w,64w+64) = 4
// j-tiles, weights all-register bregs[8][4]. As[par][16][512] i8 (rows 4..15
// stay zero). acc valid rows live in lq==0 lanes -> Rls redistribute.
__global__ __launch_bounds__(512, 1) void recur8_kernel(
    const unsigned short* __restrict__ igh,  // (T,32,8,64,4) bf16 permuted
    const float* __restrict__ ei2,           // (T,8,64) f32 permuted
    const char* __restrict__ wrec8,          // (H,H) i8
    const float* __restrict__ wscale,        // (H)
    const float* __restrict__ rbias,         // (H)
    unsigned short* __restrict__ hs,         // (T*B,512) bf16 plain
    float* __restrict__ h_last) {            // (B,H) f32
  __shared__ __align__(16) char As[2][16][512];   // 16 KB
  __shared__ float Rls[8][272];                   // 8.5 KB, stride 17
  const int tid = threadIdx.x;
  const int g = blockIdx.x;            // batch rows 4g..4g+3
  const int bb = g << 2;
  const int w = tid >> 6, l = tid & 63;
  const int lm = l & 15, lq = l >> 4;
  const int nbase = w << 6;
  const int lswz = lm & 7;
  const int n_own = nbase + (lq << 4) + lm;   // this lane's epilogue column

  // all weights register-resident: bregs[kk][j] = Wrec8[n, kk*64+lq*16 ..+16]
  int4x bregs[8][4];
#pragma unroll
  for (int kk = 0; kk < 8; ++kk)
#pragma unroll
    for (int j = 0; j < 4; ++j)
      bregs[kk][j] = *(const int4x*)(
          wrec8 + ((size_t)(nbase + j * 16 + lm) << 9) + (kk << 6) + (lq << 4));
  const float wscv = wscale[n_own] * 0.0625f;   // * (1/16) a-scale
  const float rbv  = rbias[n_own];
  // zero As both parities (rows 4..15 stay zero forever)
  {
    int4x z = {0, 0, 0, 0};
    *(int4x*)((char*)As + tid * 32) = z;
    *(int4x*)((char*)As + tid * 32 + 16) = z;
  }
  __syncthreads();

#pragma unroll 1
  for (int t = 0; t < 512; ++t) {
    const int par = t & 1, par2 = par ^ 1;
    // ig[t]: one 8B load per lane; ei[t+1]: one 4B load
    const unsigned long long igp = *(const unsigned long long*)(
        igh + ((((size_t)t * 32 + g) * 8 + w) * 64 + l) * 4);
    const float eiv =
        (t < 511) ? ei2[((size_t)((t + 1) * 8 + w) << 6) + l] : 0.f;

    // K-loop: rec = a_t @ Wrec^T (A rows 4..15 are zero)
    int4x acc[4] = {};
    const char* aRow = (const char*)As + par * 8192 + lm * 512;
#pragma unroll
    for (int kk = 0; kk < 8; ++kk) {
      int4x av = *(const int4x*)(aRow + ((((kk << 2) | lq) ^ lswz) << 4));
#pragma unroll
      for (int j = 0; j < 4; ++j)
        acc[j] = __builtin_amdgcn_mfma_i32_16x16x64_i8(av, bregs[kk][j],
                                                       acc[j], 0, 0, 0);
    }
    // redistribute: valid rows r4=0..3 live in lq==0 lanes (col = j*16+lm)
    if (lq == 0) {
#pragma unroll
      for (int j = 0; j < 4; ++j)
#pragma unroll
        for (int r4 = 0; r4 < 4; ++r4)
          Rls[w][(j * 4 + r4) * 17 + lm] = (float)acc[j][r4];
    }
    // same-wave LDS write->read is ordered; compiler inserts lgkmcnt
    float hv[4];
#pragma unroll
    for (int r = 0; r < 4; ++r) {
      float rec = Rls[w][((lq << 2) + r) * 17 + lm] * wscv;
      float z = rec + b2f((unsigned short)(igp >> (16 * r))) + rbv;
      // fast softplus: max(z,0) + log(1+exp(-|z|)), native exp/log
      float az = fabsf(z);
      hv[r] = fmaxf(z, 0.f) + __logf(1.f + __expf(-az));
    }
    if (t < 511) {
      // a_{t+1} = h*ei quantized to i8 (scale 16), swizzled byte store
#pragma unroll
      for (int r = 0; r < 4; ++r) {
        float a = hv[r] * eiv * 16.f;
        int ai = (int)rintf(fminf(fmaxf(a, -127.f), 127.f));
        ((char*)As)[par2 * 8192 + r * 512 +
                    ((((n_own >> 4) ^ r) << 4) | (n_own & 15))] = (char)ai;
      }
    }
#pragma unroll
    for (int r = 0; r < 4; ++r) {
      __builtin_nontemporal_store(
          f2b(hv[r]), hs + (((size_t)(t << 7) + bb + r) << 9) + n_own);
      if (t == 511) h_last[((bb + r) << 9) + n_own] = hv[r];
    }
    __syncthreads();   // As[par2] writes visible before next step's K-loop
  }
}

// ---------------- launch ---------------------------------------------------
extern "C" void kernel_launch(void* const* d_in, const int* in_sizes, int n_in,
                              void* d_out, int out_size, void* d_ws,
                              size_t ws_size, hipStream_t stream) {
  const float* x     = (const float*)d_in[0];
  const float* gu    = (const float*)d_in[1];
  const float* Win   = (const float*)d_in[2];
  const float* bin   = (const float*)d_in[3];
  const float* Wrec  = (const float*)d_in[4];
  const float* rbias = (const float*)d_in[5];
  const float* elog  = (const float*)d_in[6];
  const float* Wout  = (const float*)d_in[7];
  const float* bout  = (const float*)d_in[8];

  char* ws = (char*)d_ws;
  float* ei2            = (float*)ws;                        // 1 MB (4MB slot)
  unsigned short* winb  = (unsigned short*)(ws + 4194304);   // 512 KB
  unsigned short* woutb = (unsigned short*)(ws + 4718592);   // 512 KB
  char* wrec8           = (char*)(ws + 5242880);             // 256 KB
  float* wscale         = (float*)(ws + 5505024);            // 2 KB
  unsigned short* igh   = (unsigned short*)(ws + 6291456);   // 64 MB
  unsigned short* hs    = (unsigned short*)(ws + 73400320);  // 64 MB

  float* outp  = (float*)d_out;            // (T,B,O) f32
  float* hlast = outp + 33554432;          // (B,H)
  float* clast = outp + 33554432 + 65536;  // (B,H) zeros

  prep_kernel<<<1024, 256, 0, stream>>>(gu, elog, Win, Wout, ei2, winb, woutb,
                                        clast);
  wquant_kernel<<<512, 64, 0, stream>>>(Wrec, wrec8, wscale);
  gemm512<1, 1, 1><<<dim3(512, 4), 256, 0, stream>>>(x, winb, bin, igh);
  recur8_kernel<<<32, 512, 0, stream>>>(igh, ei2, wrec8, wscale, rbias, hs,
                                        hlast);
  gemm512<0, 0, 0><<<dim3(512, 4), 256, 0, stream>>>(hs, woutb, bout, outp);
}

// Round 9
// 575.013 us; speedup vs baseline: 9.9125x; 1.3653x over previous
//
#include <hip/hip_runtime.h>
#include <stdint.h>

// EISepLSTM: x(T,B,I) -> ig GEMM -> 512-step EI recurrence -> out GEMM.
// T=512, B=128, I=H=O=512.
// Round 9: round-8 intra-CU i8 design at M=1, spread over 128 CUs.
// Block = 1 batch row x full H, 512 threads (8 waves). Wave owns 64 cols,
// weights register-resident (bregs[8][4] = 128 regs -> AGPR file). a_t i8
// row in LDS (row 0 of a 16-row MFMA tile; rows 1..15 stay zero). Plain
// ig/ei/hs layouts (no permutes). ig/ei register double-buffered 1 step
// ahead. One barrier/step. No cross-block communication.

typedef __attribute__((ext_vector_type(8))) short short8;
typedef __attribute__((ext_vector_type(4))) float f32x4;
typedef __attribute__((ext_vector_type(4))) int int4x;

__device__ __forceinline__ unsigned short f2b(float f) {
  unsigned int u = __float_as_uint(f);
  u = (u + 0x7fffu + ((u >> 16) & 1u)) >> 16;   // RNE
  return (unsigned short)u;
}
__device__ __forceinline__ float b2f(unsigned short s) {
  return __uint_as_float(((unsigned int)s) << 16);
}

// ---------------- prep: ei (plain), bf16 weight casts, c_last zeros --------
__global__ void prep_kernel(const float* __restrict__ gu,      // (T,H,2)
                            const float* __restrict__ logit,   // (H,2)
                            const float* __restrict__ win,     // (H,I)
                            const float* __restrict__ wout,    // (O,H)
                            float* __restrict__ ei,            // (T,H)
                            unsigned short* __restrict__ winb,
                            unsigned short* __restrict__ woutb,
                            float* __restrict__ c_last) {
  int i = blockIdx.x * 256 + threadIdx.x;          // 0 .. 262143
  int h = i & 511;
  float u0 = gu[2 * i], u1 = gu[2 * i + 1];
  float l0 = logit[2 * h], l1 = logit[2 * h + 1];
  float g0 = -logf(-logf(u0 + 1e-10f) + 1e-10f);
  float g1 = -logf(-logf(u1 + 1e-10f) + 1e-10f);
  // softmax2 diff == tanh(dz/2), dz = ((l0+g0)-(l1+g1))/tau
  float dz = ((l0 + g0) - (l1 + g1)) * 10.0f;
  ei[i] = tanhf(0.5f * dz);
  winb[i]  = f2b(win[i]);
  woutb[i] = f2b(wout[i]);
  if (i < 65536) c_last[i] = 0.0f;
}

// ---------------- Wrec row quantization: i8 with per-row scale -------------
__global__ void wquant_kernel(const float* __restrict__ wrec,  // (H,H)
                              char* __restrict__ wrec8,        // (H,H) i8
                              float* __restrict__ wscale) {    // (H)
  const int n = blockIdx.x;          // output row 0..511
  const int l = threadIdx.x;         // 0..63
  const float* row = wrec + (size_t)n * 512 + l * 8;
  float v[8];
  float m = 0.f;
#pragma unroll
  for (int e = 0; e < 8; ++e) {
    v[e] = fmaxf(row[e], 0.f);
    m = fmaxf(m, v[e]);
  }
#pragma unroll
  for (int off = 32; off >= 1; off >>= 1) m = fmaxf(m, __shfl_down(m, off));
  m = __shfl(m, 0);
  const float s = (m > 0.f) ? (m / 127.f) : 1.f;
  const float inv = 1.f / s;
  unsigned long long pk = 0;
#pragma unroll
  for (int e = 0; e < 8; ++e) {
    int q = (int)rintf(v[e] * inv);
    pk |= ((unsigned long long)(unsigned char)(char)q) << (8 * e);
  }
  *(unsigned long long*)(wrec8 + (size_t)n * 512 + l * 8) = pk;
  if (l == 0) wscale[n] = s;
}

// ---------------- GEMM: C[m,n] = sum_k A[m,k]*W[n,k] + bias[n] -------------
// A: M x 512 (f32 or bf16), W: 512 x 512 bf16 row-major, out f32 or bf16.
template <int A_F32, int OUT_BF16>
__global__ __launch_bounds__(256, 2) void gemm512(
    const void* __restrict__ Ap, const unsigned short* __restrict__ W,
    const float* __restrict__ bias, void* __restrict__ Cp) {
  __shared__ __align__(16) unsigned short Al[128][32];
  __shared__ __align__(16) unsigned short Bl[128][32];
  const int tid = threadIdx.x;
  const int w = tid >> 6, l = tid & 63;
  const int wr = w >> 1, wc = w & 1;
  const int lm = l & 15, lq = l >> 4;
  const size_t m0 = (size_t)blockIdx.x * 128;
  const int n0 = blockIdx.y * 128;
  const int r = tid >> 1;             // staging row 0..127
  const int sb = (tid & 1) << 1;      // staging slot base (16B slots): 0 or 2
  f32x4 acc[4][4] = {};

  for (int kt = 0; kt < 16; ++kt) {
    const int k0 = kt << 5;
    // stage A tile
    {
      char* dst = (char*)Al + r * 64;
      if (A_F32) {
        const float* A = (const float*)Ap + (m0 + r) * 512 + k0 + (sb << 3);
#pragma unroll
        for (int j = 0; j < 2; ++j) {
          float4 v0 = ((const float4*)A)[2 * j + 0];
          float4 v1 = ((const float4*)A)[2 * j + 1];
          short8 o;
          o[0] = (short)f2b(v0.x); o[1] = (short)f2b(v0.y);
          o[2] = (short)f2b(v0.z); o[3] = (short)f2b(v0.w);
          o[4] = (short)f2b(v1.x); o[5] = (short)f2b(v1.y);
          o[6] = (short)f2b(v1.z); o[7] = (short)f2b(v1.w);
          *(short8*)(dst + (((sb + j + (r >> 1)) & 3) << 4)) = o;
        }
      } else {
        const unsigned short* A =
            (const unsigned short*)Ap + (m0 + r) * 512 + k0 + (sb << 3);
#pragma unroll
        for (int j = 0; j < 2; ++j)
          *(short8*)(dst + (((sb + j + (r >> 1)) & 3) << 4)) =
              *(const short8*)(A + 8 * j);
      }
      // stage W tile
      const unsigned short* Wp = W + ((size_t)(n0 + r) << 9) + k0 + (sb << 3);
      char* dstB = (char*)Bl + r * 64;
#pragma unroll
      for (int j = 0; j < 2; ++j)
        *(short8*)(dstB + (((sb + j + (r >> 1)) & 3) << 4)) =
            *(const short8*)(Wp + 8 * j);
    }
    __syncthreads();
    short8 af[4], bf[4];
#pragma unroll
    for (int i = 0; i < 4; ++i) {
      int row = wr * 64 + i * 16 + lm;
      af[i] = *(const short8*)((char*)Al + row * 64 +
                               (((lq + (row >> 1)) & 3) << 4));
    }
#pragma unroll
    for (int j = 0; j < 4; ++j) {
      int row = wc * 64 + j * 16 + lm;
      bf[j] = *(const short8*)((char*)Bl + row * 64 +
                               (((lq + (row >> 1)) & 3) << 4));
    }
#pragma unroll
    for (int i = 0; i < 4; ++i)
#pragma unroll
      for (int j = 0; j < 4; ++j)
        acc[i][j] =
            __builtin_amdgcn_mfma_f32_16x16x32_bf16(af[i], bf[j], acc[i][j], 0, 0, 0);
    __syncthreads();
  }
  float bv[4];
#pragma unroll
  for (int j = 0; j < 4; ++j) bv[j] = bias[n0 + wc * 64 + j * 16 + lm];
#pragma unroll
  for (int i = 0; i < 4; ++i) {
#pragma unroll
    for (int r4 = 0; r4 < 4; ++r4) {
      size_t gm = m0 + wr * 64 + i * 16 + lq * 4 + r4;
#pragma unroll
      for (int j = 0; j < 4; ++j) {
        int gn = n0 + wc * 64 + j * 16 + lm;
        float v = acc[i][j][r4] + bv[j];
        if (OUT_BF16)
          ((unsigned short*)Cp)[(gm << 9) + gn] = f2b(v);
        else
          ((float*)Cp)[(gm << 9) + gn] = v;
      }
    }
  }
}

// ---------------- recurrence (M=1, 128 blocks x 8 waves) -------------------
// block g: batch row g, full H. wave w: cols [64w,64w+64) = 4 j-tiles,
// weights all-register bregs[8][4]. As[par][16][512] i8, only row 0 live.
// acc valid element: [j][0] in lq==0 lanes -> Rls redistribute (per-wave).
__global__ __launch_bounds__(512, 1) void recur9_kernel(
    const unsigned short* __restrict__ ig,   // (T*B,512) bf16 plain
    const float* __restrict__ ei,            // (T,512) f32 plain
    const char* __restrict__ wrec8,          // (H,H) i8
    const float* __restrict__ wscale,        // (H)
    const float* __restrict__ rbias,         // (H)
    unsigned short* __restrict__ hs,         // (T*B,512) bf16 plain
    float* __restrict__ h_last) {            // (B,H) f32
  __shared__ __align__(16) char As[2][16][512];   // 16 KB
  __shared__ float Rls[8][68];                    // 2.2 KB
  const int tid = threadIdx.x;
  const int g = blockIdx.x;            // batch row
  const int w = tid >> 6, l = tid & 63;
  const int lm = l & 15, lq = l >> 4;
  const int nbase = w << 6;
  const int lswz = lm & 7;
  const int n_own = nbase + l;         // this lane's column (identity layout)

  // all weights register-resident: bregs[kk][j] = Wrec8[n, kk*64+lq*16 ..+16]
  int4x bregs[8][4];
#pragma unroll
  for (int kk = 0; kk < 8; ++kk)
#pragma unroll
    for (int j = 0; j < 4; ++j)
      bregs[kk][j] = *(const int4x*)(
          wrec8 + ((size_t)(nbase + j * 16 + lm) << 9) + (kk << 6) + (lq << 4));
  const float wscv = wscale[n_own] * 0.0625f;   // * (1/16) a-scale
  const float rbv  = rbias[n_own];
  // zero As both parities (rows 1..15 stay zero forever)
  {
    int4x z = {0, 0, 0, 0};
    *(int4x*)((char*)As + tid * 32) = z;
    *(int4x*)((char*)As + tid * 32 + 16) = z;
  }
  __syncthreads();

  // register double-buffer of ig[t] and ei[t+1] (1 step ahead)
  const unsigned short* igp = ig + ((size_t)g << 9) + n_own;  // t-stride 65536
  unsigned short ig_cur = igp[0];
  float ei_cur = ei[512 + n_own];

#pragma unroll 1
  for (int t = 0; t < 512; ++t) {
    const int par = t & 1, par2 = par ^ 1;
    // issue next-step loads (consumed after K-loop next iteration)
    unsigned short ig_nxt = 0;
    float ei_nxt = 0.f;
    if (t < 511)
      ig_nxt = __builtin_nontemporal_load(igp + (size_t)(t + 1) * 65536);
    if (t < 510) ei_nxt = ei[(size_t)(t + 2) * 512 + n_own];

    // K-loop: rec = a_t @ Wrec^T (A rows 1..15 zero)
    int4x acc[4] = {};
    const char* aRow = (const char*)As + par * 8192 + lm * 512;
#pragma unroll
    for (int kk = 0; kk < 8; ++kk) {
      int4x av = *(const int4x*)(aRow + ((((kk << 2) | lq) ^ lswz) << 4));
#pragma unroll
      for (int j = 0; j < 4; ++j)
        acc[j] = __builtin_amdgcn_mfma_i32_16x16x64_i8(av, bregs[kk][j],
                                                       acc[j], 0, 0, 0);
    }
    // redistribute: valid value acc[j][0] lives in lq==0 lanes (col j*16+lm)
    if (lq == 0) {
#pragma unroll
      for (int j = 0; j < 4; ++j) Rls[w][j * 17 + lm] = (float)acc[j][0];
    }
    // same-wave LDS write->read: hardware-ordered via lgkmcnt
    float rec = Rls[w][lq * 17 + lm] * wscv;
    float z = rec + b2f(ig_cur) + rbv;
    // fast softplus: max(z,0) + log(1+exp(-|z|)), native exp/log
    float az = fabsf(z);
    float h = fmaxf(z, 0.f) + __logf(1.f + __expf(-az));
    if (t < 511) {
      // a_{t+1} = h*ei quantized to i8 (scale 16); row 0, plain position
      float a = h * ei_cur * 16.f;
      int ai = (int)rintf(fminf(fmaxf(a, -127.f), 127.f));
      ((char*)As)[par2 * 8192 + n_own] = (char)ai;
    }
    __builtin_nontemporal_store(
        f2b(h), hs + (((size_t)t * 128 + g) << 9) + n_own);
    if (t == 511) h_last[((size_t)g << 9) + n_own] = h;
    ig_cur = ig_nxt;
    ei_cur = ei_nxt;
    __syncthreads();   // As[par2] visible before next step's K-loop
  }
}

// ---------------- launch ---------------------------------------------------
extern "C" void kernel_launch(void* const* d_in, const int* in_sizes, int n_in,
                              void* d_out, int out_size, void* d_ws,
                              size_t ws_size, hipStream_t stream) {
  const float* x     = (const float*)d_in[0];
  const float* gu    = (const float*)d_in[1];
  const float* Win   = (const float*)d_in[2];
  const float* bin   = (const float*)d_in[3];
  const float* Wrec  = (const float*)d_in[4];
  const float* rbias = (const float*)d_in[5];
  const float* elog  = (const float*)d_in[6];
  const float* Wout  = (const float*)d_in[7];
  const float* bout  = (const float*)d_in[8];

  char* ws = (char*)d_ws;
  float* ei             = (float*)ws;                        // 1 MB
  unsigned short* winb  = (unsigned short*)(ws + 4194304);   // 512 KB
  unsigned short* woutb = (unsigned short*)(ws + 4718592);   // 512 KB
  char* wrec8           = (char*)(ws + 5242880);             // 256 KB
  float* wscale         = (float*)(ws + 5505024);            // 2 KB
  unsigned short* igb   = (unsigned short*)(ws + 6291456);   // 64 MB
  unsigned short* hs    = (unsigned short*)(ws + 73400320);  // 64 MB

  float* outp  = (float*)d_out;            // (T,B,O) f32
  float* hlast = outp + 33554432;          // (B,H)
  float* clast = outp + 33554432 + 65536;  // (B,H) zeros

  prep_kernel<<<1024, 256, 0, stream>>>(gu, elog, Win, Wout, ei, winb, woutb,
                                        clast);
  wquant_kernel<<<512, 64, 0, stream>>>(Wrec, wrec8, wscale);
  gemm512<1, 1><<<dim3(512, 4), 256, 0, stream>>>(x, winb, bin, igb);
  recur9_kernel<<<128, 512, 0, stream>>>(igb, ei, wrec8, wscale, rbias, hs,
                                         hlast);
  gemm512<0, 0><<<dim3(512, 4), 256, 0, stream>>>(hs, woutb, bout, outp);
}